// Round 6
// baseline (320.469 us; speedup 1.0000x reference)
//
#include <hip/hip_runtime.h>
#include <stdint.h>

#define SEQ   2048
#define DMODEL 2048
#define NQH   32
#define NKVH  8
#define HDIM  64
#define QN    (NQH*HDIM)    // 2048
#define KVNN  (NKVH*HDIM)   // 512

typedef __bf16 bf16x8 __attribute__((ext_vector_type(8)));
typedef float  f32x4  __attribute__((ext_vector_type(4)));
typedef unsigned short u16;

__device__ __forceinline__ u16 f2bf(float f) {
  uint32_t u = __builtin_bit_cast(uint32_t, f);
  u += 0x7fffu + ((u >> 16) & 1u);   // RNE
  return (u16)(u >> 16);
}
__device__ __forceinline__ float bf2f(u16 b) {
  return __builtin_bit_cast(float, (uint32_t)b << 16);
}
__device__ __forceinline__ bool probe_is_f32(const uint32_t* p) {
  return (p[0] & 0xFFFFu) == 0u;   // cos[0]=1.0: f32->0x3F800000, bf16 pair->0x3F803F80
}

// ---------------------------------------------------------------------------
// Fused input conversion: all 7 inputs -> bf16 copies in ws (8 elts/thread).
// ---------------------------------------------------------------------------
__global__ __launch_bounds__(256)
void conv_all(const void* __restrict__ X, const void* __restrict__ cosv,
              const void* __restrict__ sinv, const void* __restrict__ wq,
              const void* __restrict__ wk, const void* __restrict__ wv,
              const void* __restrict__ wo,
              u16* __restrict__ Xc, u16* __restrict__ cosc, u16* __restrict__ sinc,
              u16* __restrict__ wqc, u16* __restrict__ wkc, u16* __restrict__ wvc,
              u16* __restrict__ woc)
{
  const bool f32in = probe_is_f32((const uint32_t*)cosv);
  const long t = (long)blockIdx.x * 256 + threadIdx.x;
  const void* src; u16* dst; long off;
  if      (t < 524288L)  { src = X;    dst = Xc;   off = t; }
  else if (t < 1048576L) { src = wq;   dst = wqc;  off = t - 524288L; }
  else if (t < 1179648L) { src = wk;   dst = wkc;  off = t - 1048576L; }
  else if (t < 1310720L) { src = wv;   dst = wvc;  off = t - 1179648L; }
  else if (t < 1835008L) { src = wo;   dst = woc;  off = t - 1310720L; }
  else if (t < 1851392L) { src = cosv; dst = cosc; off = t - 1835008L; }
  else                   { src = sinv; dst = sinc; off = t - 1851392L; }
  if (f32in) {
    const float4* s = (const float4*)src;
    float4 a = s[2*off], b = s[2*off + 1];
    union { u16 h[8]; uint4 u; } o;
    o.h[0]=f2bf(a.x); o.h[1]=f2bf(a.y); o.h[2]=f2bf(a.z); o.h[3]=f2bf(a.w);
    o.h[4]=f2bf(b.x); o.h[5]=f2bf(b.y); o.h[6]=f2bf(b.z); o.h[7]=f2bf(b.w);
    *(uint4*)(dst + off*8) = o.u;
  } else {
    *(uint4*)(dst + off*8) = ((const uint4*)src)[off];
  }
}

// ---------------------------------------------------------------------------
// Merged QKV projection: C = X @ [Wq;Wk;Wv]^T over N=3072, 128x128 tiles.
// ---------------------------------------------------------------------------
__global__ __launch_bounds__(256, 2)
void gemm_qkv(const u16* __restrict__ A,
              const u16* __restrict__ wq, const u16* __restrict__ wk,
              const u16* __restrict__ wv,
              u16* __restrict__ Qb, u16* __restrict__ Kb, u16* __restrict__ Vb)
{
  __shared__ __align__(16) u16 As[128][40];
  __shared__ __align__(16) u16 Bs[128][40];
  const int tid  = threadIdx.x;
  const int wave = tid >> 6;
  const int lane = tid & 63;
  const int quad = lane >> 4;
  const int l16  = lane & 15;
  const int m0 = blockIdx.y * 128;
  const int n0 = blockIdx.x * 128;
  const int wm = (wave >> 1) * 64;
  const int wn = (wave & 1) * 64;
  const int srow = tid >> 2;
  const int scol = (tid & 3) * 8;
  const int K = DMODEL;

  const u16* Bbase; u16* Cbase; int Cstride, nc0;
  if (n0 < 2048)      { Bbase = wq + (size_t)n0 * K;          Cbase = Qb; Cstride = QN;   nc0 = n0; }
  else if (n0 < 2560) { Bbase = wk + (size_t)(n0 - 2048) * K; Cbase = Kb; Cstride = KVNN; nc0 = n0 - 2048; }
  else                { Bbase = wv + (size_t)(n0 - 2560) * K; Cbase = Vb; Cstride = KVNN; nc0 = n0 - 2560; }

  f32x4 acc[4][4];
  #pragma unroll
  for (int i = 0; i < 4; i++)
    #pragma unroll
    for (int j = 0; j < 4; j++)
      acc[i][j] = (f32x4){0.f, 0.f, 0.f, 0.f};

  for (int k0 = 0; k0 < K; k0 += 32) {
    uint4 a0 = *(const uint4*)(A + (size_t)(m0 + srow)      * K + k0 + scol);
    uint4 a1 = *(const uint4*)(A + (size_t)(m0 + srow + 64) * K + k0 + scol);
    uint4 b0 = *(const uint4*)(Bbase + (size_t)(srow)      * K + k0 + scol);
    uint4 b1 = *(const uint4*)(Bbase + (size_t)(srow + 64) * K + k0 + scol);
    __syncthreads();
    *(uint4*)&As[srow][scol]      = a0;
    *(uint4*)&As[srow + 64][scol] = a1;
    *(uint4*)&Bs[srow][scol]      = b0;
    *(uint4*)&Bs[srow + 64][scol] = b1;
    __syncthreads();
    bf16x8 af[4], bfr[4];
    #pragma unroll
    for (int i = 0; i < 4; i++) af[i]  = *(const bf16x8*)&As[wm + i*16 + l16][quad*8];
    #pragma unroll
    for (int j = 0; j < 4; j++) bfr[j] = *(const bf16x8*)&Bs[wn + j*16 + l16][quad*8];
    #pragma unroll
    for (int i = 0; i < 4; i++)
      #pragma unroll
      for (int j = 0; j < 4; j++)
        acc[i][j] = __builtin_amdgcn_mfma_f32_16x16x32_bf16(af[i], bfr[j], acc[i][j], 0, 0, 0);
  }

  #pragma unroll
  for (int i = 0; i < 4; i++) {
    const int rb = m0 + wm + i*16 + quad*4;
    #pragma unroll
    for (int j = 0; j < 4; j++) {
      const int col = nc0 + wn + j*16 + l16;
      #pragma unroll
      for (int r = 0; r < 4; r++)
        Cbase[(size_t)(rb + r) * Cstride + col] = f2bf(acc[i][j][r]);
    }
  }
}

// ---------------------------------------------------------------------------
// O-projection GEMM. f32 or bf16 output per probe.
// ---------------------------------------------------------------------------
__global__ __launch_bounds__(256, 2)
void gemm_nt(const u16* __restrict__ A, const u16* __restrict__ B,
             void* __restrict__ C, int M, int N, int K,
             const uint32_t* outprobe)
{
  __shared__ __align__(16) u16 As[128][40];
  __shared__ __align__(16) u16 Bs[128][40];
  const int tid  = threadIdx.x;
  const int wave = tid >> 6;
  const int lane = tid & 63;
  const int quad = lane >> 4;
  const int l16  = lane & 15;
  const int m0 = blockIdx.y * 128;
  const int n0 = blockIdx.x * 128;
  const int wm = (wave >> 1) * 64;
  const int wn = (wave & 1) * 64;
  const int srow = tid >> 2;
  const int scol = (tid & 3) * 8;

  f32x4 acc[4][4];
  #pragma unroll
  for (int i = 0; i < 4; i++)
    #pragma unroll
    for (int j = 0; j < 4; j++)
      acc[i][j] = (f32x4){0.f, 0.f, 0.f, 0.f};

  for (int k0 = 0; k0 < K; k0 += 32) {
    uint4 a0 = *(const uint4*)(A + (size_t)(m0 + srow)      * K + k0 + scol);
    uint4 a1 = *(const uint4*)(A + (size_t)(m0 + srow + 64) * K + k0 + scol);
    uint4 b0 = *(const uint4*)(B + (size_t)(n0 + srow)      * K + k0 + scol);
    uint4 b1 = *(const uint4*)(B + (size_t)(n0 + srow + 64) * K + k0 + scol);
    __syncthreads();
    *(uint4*)&As[srow][scol]      = a0;
    *(uint4*)&As[srow + 64][scol] = a1;
    *(uint4*)&Bs[srow][scol]      = b0;
    *(uint4*)&Bs[srow + 64][scol] = b1;
    __syncthreads();
    bf16x8 af[4], bfr[4];
    #pragma unroll
    for (int i = 0; i < 4; i++) af[i]  = *(const bf16x8*)&As[wm + i*16 + l16][quad*8];
    #pragma unroll
    for (int j = 0; j < 4; j++) bfr[j] = *(const bf16x8*)&Bs[wn + j*16 + l16][quad*8];
    #pragma unroll
    for (int i = 0; i < 4; i++)
      #pragma unroll
      for (int j = 0; j < 4; j++)
        acc[i][j] = __builtin_amdgcn_mfma_f32_16x16x32_bf16(af[i], bfr[j], acc[i][j], 0, 0, 0);
  }

  const bool f32out = (outprobe != nullptr) && probe_is_f32(outprobe);
  #pragma unroll
  for (int i = 0; i < 4; i++) {
    const int rb = m0 + wm + i*16 + quad*4;
    #pragma unroll
    for (int j = 0; j < 4; j++) {
      const int col = n0 + wn + j*16 + l16;
      if (f32out) {
        float* Cf = (float*)C;
        #pragma unroll
        for (int r = 0; r < 4; r++)
          Cf[(size_t)(rb + r) * N + col] = acc[i][j][r];
      } else {
        u16* Ch = (u16*)C;
        #pragma unroll
        for (int r = 0; r < 4; r++)
          Ch[(size_t)(rb + r) * N + col] = f2bf(acc[i][j][r]);
      }
    }
  }
}

// ---------------------------------------------------------------------------
// RoPE in-place on K only (Q rope is fused into attn). [SEQ][512].
// ---------------------------------------------------------------------------
__global__ void rope_k(u16* __restrict__ Kb,
                       const u16* __restrict__ cosb, const u16* __restrict__ sinb)
{
  const int idx = blockIdx.x * 256 + threadIdx.x;   // SEQ*NKVH*32 = 524288
  const int s = idx >> 8;
  const int rem = idx & 255;
  u16* base = Kb + (size_t)s * KVNN + (rem >> 5) * 64;
  const int d = rem & 31;
  const float x1 = bf2f(base[d]);
  const float x2 = bf2f(base[d + 32]);
  const float c  = bf2f(cosb[s * 64 + d]);     // cos[d+32] == cos[d]
  const float sn = bf2f(sinb[s * 64 + d]);
  base[d]      = f2bf(x1 * c - x2 * sn);
  base[d + 32] = f2bf(x2 * c + x1 * sn);
}

// ---------------------------------------------------------------------------
// Global V transpose: Vb [SEQ][512] -> Vtg [8][64][SEQ]  (per-kvh [d][s]).
// ---------------------------------------------------------------------------
__global__ __launch_bounds__(256)
void vtrans(const u16* __restrict__ Vb, u16* __restrict__ Vtg)
{
  __shared__ __align__(16) u16 T[64][72];
  const int tid = threadIdx.x;
  const int hkv = blockIdx.x & 7;
  const int s0  = (blockIdx.x >> 3) * 64;
  const int r = tid >> 3;            // 0..31
  const int c = (tid & 7) * 8;       // 0..56
  *(uint4*)&T[r][c]      = *(const uint4*)(Vb + (size_t)(s0 + r)      * KVNN + hkv*64 + c);
  *(uint4*)&T[r + 32][c] = *(const uint4*)(Vb + (size_t)(s0 + r + 32) * KVNN + hkv*64 + c);
  __syncthreads();
  #pragma unroll
  for (int dd = 0; dd < 64; dd += 32) {
    const int d = (tid >> 3) + dd;
    union { u16 h[8]; uint4 u; } o;
    #pragma unroll
    for (int j = 0; j < 8; j++) o.h[j] = T[c + j][d];
    *(uint4*)(Vtg + (size_t)(hkv*64 + d) * SEQ + s0 + c) = o.u;
  }
}

// ---------------------------------------------------------------------------
// Causal GQA flash attention, v3: barrier-free, wave-private.
// Wave = (head, 32-q-row tile). K-frags and V^T-frags load DIRECTLY from
// global (L1/L2-resident; block's 4 waves = 4 heads of same kv-group & same
// tile -> shared K/V stream in L1). Only LDS use: wave-private P round-trip.
// Q RoPE + 1/8 scale fused into the one-time Q-frag load.
// Heavy tiles dispatch first (tile = 63 - u/32) to kill the tail.
// ---------------------------------------------------------------------------
__device__ __forceinline__ float qmax16(float v) {
  v = fmaxf(v, __shfl_xor(v, 1)); v = fmaxf(v, __shfl_xor(v, 2));
  v = fmaxf(v, __shfl_xor(v, 4)); v = fmaxf(v, __shfl_xor(v, 8));
  return v;
}
__device__ __forceinline__ float qsum16(float v) {
  v += __shfl_xor(v, 1); v += __shfl_xor(v, 2);
  v += __shfl_xor(v, 4); v += __shfl_xor(v, 8);
  return v;
}

__global__ __launch_bounds__(256, 2)
void attn_kernel(const u16* __restrict__ Qb,   // [SEQ][2048] pre-rope
                 const u16* __restrict__ Kb,   // [SEQ][512]  RoPE'd
                 const u16* __restrict__ Vtg,  // [8][64][SEQ]
                 u16* __restrict__ Ob,         // [SEQ][2048]
                 const u16* __restrict__ cosb, const u16* __restrict__ sinb)
{
  __shared__ __align__(16) u16 Ps[4][32][72];
  const int tid  = threadIdx.x;
  const int wave = tid >> 6;
  const int lane = tid & 63;
  const int quad = lane >> 4;
  const int l16  = lane & 15;
  const int u    = blockIdx.x * 4 + wave;   // 0..2047
  const int h    = u & 31;
  const int tile = 63 - (u >> 5);           // heavy first
  const int hkv  = h >> 2;
  const int trow0 = tile * 32;
  const int ktmax = (tile >> 1) + 1;

  // ---- one-time Q load + fused RoPE + 1/8 scale (A-layout frags) ----
  bf16x8 qf[2][2];
  #pragma unroll
  for (int mt = 0; mt < 2; mt++) {
    const int qrow = trow0 + mt*16 + l16;
    const u16* qp = Qb + (size_t)qrow * QN + h*64 + quad*8;
    union { bf16x8 v; u16 h8[8]; } lo, hi, cv, sv, olo, ohi;
    lo.v = *(const bf16x8*)qp;
    hi.v = *(const bf16x8*)(qp + 32);
    cv.v = *(const bf16x8*)(cosb + qrow*64 + quad*8);   // cos[d+32]==cos[d]
    sv.v = *(const bf16x8*)(sinb + qrow*64 + quad*8);
    #pragma unroll
    for (int j = 0; j < 8; j++) {
      const float x1 = bf2f(lo.h8[j]), x2 = bf2f(hi.h8[j]);
      const float c = bf2f(cv.h8[j]), sn = bf2f(sv.h8[j]);
      olo.h8[j] = f2bf((x1*c - x2*sn) * 0.125f);
      ohi.h8[j] = f2bf((x2*c + x1*sn) * 0.125f);
    }
    qf[mt][0] = olo.v;
    qf[mt][1] = ohi.v;
  }

  f32x4 oacc[2][4];
  #pragma unroll
  for (int mt = 0; mt < 2; mt++)
    #pragma unroll
    for (int nt = 0; nt < 4; nt++)
      oacc[mt][nt] = (f32x4){0.f, 0.f, 0.f, 0.f};
  float m_run[2][4], l_run[2][4];
  #pragma unroll
  for (int mt = 0; mt < 2; mt++)
    #pragma unroll
    for (int r = 0; r < 4; r++) { m_run[mt][r] = -1e30f; l_run[mt][r] = 0.f; }

  for (int kt = 0; kt < ktmax; kt++) {
    const int kb = kt * 64;
    const bool last  = (kt == ktmax - 1);
    const bool halfT = last && ((tile & 1) == 0);  // even tile: keys 32..63 dead

    // ---- V^T frags (prefetch early; dead half skipped) ----
    bf16x8 vf[2][4];
    #pragma unroll
    for (int ks = 0; ks < 2; ks++) {
      if (halfT && ks == 1) continue;
      #pragma unroll
      for (int nt = 0; nt < 4; nt++)
        vf[ks][nt] = *(const bf16x8*)(Vtg + (size_t)(hkv*64 + nt*16 + l16) * SEQ
                                          + kb + ks*32 + quad*8);
    }
    // ---- S = Q @ K^T (K frags direct from global) ----
    f32x4 sacc[2][4];
    #pragma unroll
    for (int mt = 0; mt < 2; mt++)
      #pragma unroll
      for (int nt = 0; nt < 4; nt++)
        sacc[mt][nt] = (f32x4){0.f, 0.f, 0.f, 0.f};
    #pragma unroll
    for (int ks = 0; ks < 2; ks++) {
      bf16x8 kf[4];
      #pragma unroll
      for (int nt = 0; nt < 4; nt++) {
        if (halfT && nt >= 2) continue;
        kf[nt] = *(const bf16x8*)(Kb + (size_t)(kb + nt*16 + l16) * KVNN
                                     + hkv*64 + ks*32 + quad*8);
      }
      #pragma unroll
      for (int nt = 0; nt < 4; nt++) {
        if (halfT && nt >= 2) continue;
        sacc[0][nt] = __builtin_amdgcn_mfma_f32_16x16x32_bf16(qf[0][ks], kf[nt], sacc[0][nt], 0,0,0);
        sacc[1][nt] = __builtin_amdgcn_mfma_f32_16x16x32_bf16(qf[1][ks], kf[nt], sacc[1][nt], 0,0,0);
      }
    }
    // ---- causal mask on the last tile ----
    if (last) {
      #pragma unroll
      for (int mt = 0; mt < 2; mt++)
        #pragma unroll
        for (int nt = 0; nt < 4; nt++)
          #pragma unroll
          for (int r = 0; r < 4; r++) {
            if (halfT && nt >= 2) { sacc[mt][nt][r] = -1e30f; continue; }
            if (kb + nt*16 + l16 > trow0 + mt*16 + quad*4 + r)
              sacc[mt][nt][r] = -1e30f;
          }
    }
    // ---- online softmax ----
    float alpha[2][4];
    #pragma unroll
    for (int mt = 0; mt < 2; mt++)
      #pragma unroll
      for (int r = 0; r < 4; r++) {
        float mx = fmaxf(fmaxf(sacc[mt][0][r], sacc[mt][1][r]),
                         fmaxf(sacc[mt][2][r], sacc[mt][3][r]));
        mx = qmax16(mx);
        const float mnew = fmaxf(m_run[mt][r], mx);
        alpha[mt][r] = __expf(m_run[mt][r] - mnew);
        m_run[mt][r] = mnew;
        float rs = 0.f;
        #pragma unroll
        for (int nt = 0; nt < 4; nt++) {
          const float p = __expf(sacc[mt][nt][r] - mnew);
          rs += p;
          Ps[wave][mt*16 + quad*4 + r][nt*16 + l16] = f2bf(p);   // C-layout
        }
        rs = qsum16(rs);
        l_run[mt][r] = l_run[mt][r] * alpha[mt][r] + rs;
      }
    #pragma unroll
    for (int mt = 0; mt < 2; mt++)
      #pragma unroll
      for (int nt = 0; nt < 4; nt++)
        #pragma unroll
        for (int r = 0; r < 4; r++)
          oacc[mt][nt][r] *= alpha[mt][r];
    // keep Ps vector loads below the scalar Ps stores (wave-private, in-order DS)
    asm volatile("" ::: "memory");
    // ---- O += P @ V ----
    #pragma unroll
    for (int ks = 0; ks < 2; ks++) {
      if (halfT && ks == 1) continue;
      bf16x8 pf0 = *(const bf16x8*)&Ps[wave][l16][ks*32 + quad*8];
      bf16x8 pf1 = *(const bf16x8*)&Ps[wave][16 + l16][ks*32 + quad*8];
      #pragma unroll
      for (int nt = 0; nt < 4; nt++) {
        oacc[0][nt] = __builtin_amdgcn_mfma_f32_16x16x32_bf16(pf0, vf[ks][nt], oacc[0][nt], 0,0,0);
        oacc[1][nt] = __builtin_amdgcn_mfma_f32_16x16x32_bf16(pf1, vf[ks][nt], oacc[1][nt], 0,0,0);
      }
    }
  }

  // ---- epilogue ----
  #pragma unroll
  for (int mt = 0; mt < 2; mt++)
    #pragma unroll
    for (int r = 0; r < 4; r++) {
      const float inv = 1.0f / l_run[mt][r];
      const int qrow = trow0 + mt*16 + quad*4 + r;
      #pragma unroll
      for (int nt = 0; nt < 4; nt++)
        Ob[(size_t)qrow * QN + h*64 + nt*16 + l16] = f2bf(oacc[mt][nt][r] * inv);
    }
}

// ---------------------------------------------------------------------------
extern "C" void kernel_launch(void* const* d_in, const int* in_sizes, int n_in,
                              void* d_out, int out_size, void* d_ws, size_t ws_size,
                              hipStream_t stream) {
  const void* X    = d_in[0];
  const void* cosr = d_in[1];
  const void* sinr = d_in[2];
  const void* wq   = d_in[3];
  const void* wk   = d_in[4];
  const void* wv   = d_in[5];
  const void* wo   = d_in[6];

  char* ws = (char*)d_ws;
  const size_t MB = 1024u * 1024u;
  u16* Xc   = (u16*)(ws);                      // 8 MB
  u16* wqc  = (u16*)(ws + 8*MB);               // 8 MB (Ab aliases after QKV gemm)
  u16* wkc  = (u16*)(ws + 16*MB);              // 2 MB
  u16* wvc  = (u16*)(ws + 18*MB);              // 2 MB
  u16* woc  = (u16*)(ws + 20*MB);              // 8 MB
  u16* cosc = (u16*)(ws + 28*MB);              // 256 KB
  u16* sinc = (u16*)(ws + 28*MB + 256*1024);   // 256 KB
  u16* Qb   = (u16*)(ws + 28*MB + 512*1024);   // 8 MB
  u16* Kb   = (u16*)(ws + 36*MB + 512*1024);   // 2 MB
  u16* Vb   = (u16*)(ws + 38*MB + 512*1024);   // 2 MB
  u16* Vtg  = (u16*)(ws + 40*MB + 512*1024);   // 2 MB
  u16* Ab   = wqc;   // wqc dead after gemm_qkv

  dim3 blk(256);
  conv_all<<<dim3(7296), blk, 0, stream>>>(X, cosr, sinr, wq, wk, wv, wo,
                                           Xc, cosc, sinc, wqc, wkc, wvc, woc);
  gemm_qkv<<<dim3(24, 16), blk, 0, stream>>>(Xc, wqc, wkc, wvc, Qb, Kb, Vb);
  rope_k<<<dim3((SEQ*NKVH*32)/256), blk, 0, stream>>>(Kb, cosc, sinc);
  vtrans<<<dim3(256), blk, 0, stream>>>(Vb, Vtg);
  attn_kernel<<<dim3(512), blk, 0, stream>>>(Qb, Kb, Vtg, Ab, cosc, sinc);
  gemm_nt<<<dim3(16, 16), blk, 0, stream>>>(Ab, woc, d_out, SEQ, DMODEL, DMODEL,
                                            (const uint32_t*)cosr);
}